// Round 18
// baseline (171.602 us; speedup 1.0000x reference)
//
#include <hip/hip_runtime.h>

#define B_ 2
#define S_ 2048
#define D_ 1024
#define H_ 16

typedef unsigned short u16;
typedef unsigned long long u64;
typedef __bf16 bf16x8 __attribute__((ext_vector_type(8)));
typedef float f32x4 __attribute__((ext_vector_type(4)));
typedef unsigned short u16x8 __attribute__((ext_vector_type(8)));
typedef unsigned short u16x4 __attribute__((ext_vector_type(4)));
typedef unsigned uint4v __attribute__((ext_vector_type(4)));

__device__ __forceinline__ unsigned swz128(unsigned o) {  // 128B rows
  return o ^ (((o >> 7) & 7) << 4);
}
__device__ __forceinline__ unsigned swz256(unsigned o) {  // 256B rows
  return o ^ (((o >> 8) & 7) << 4);
}

// bijective XCD-aware remap (nwg % 8 == 0): XCD x gets contiguous chunk.
__device__ __forceinline__ unsigned xcd_swz(unsigned id, unsigned cpx) {
  return (id & 7) * cpx + (id >> 3);
}

__device__ __forceinline__ void gload_lds16(const void* g, void* l) {
  __builtin_amdgcn_global_load_lds(
      (const __attribute__((address_space(1))) unsigned*)g,
      (__attribute__((address_space(3))) unsigned*)l, 16, 0, 0);
}

__device__ __forceinline__ u16 f2bf(float f) {
  union { float f; unsigned u; } v;
  v.f = f;
  unsigned u = v.u;
  return (u16)((u + 0x7fffu + ((u >> 16) & 1u)) >> 16);
}

__device__ __forceinline__ float bf2f(u16 x) {
  union { unsigned u; float f; } v;
  v.u = ((unsigned)x) << 16;
  return v.f;
}

// RNE pack of two f32 -> one dword of 2 bf16 (lo,hi). gfx950 HW instruction.
__device__ __forceinline__ unsigned cvtpk(float lo, float hi) {
  unsigned d;
  asm("v_cvt_pk_bf16_f32 %0, %1, %2" : "=v"(d) : "v"(lo), "v"(hi));
  return d;
}

__device__ __forceinline__ float max3f(float a, float b, float c) {
  float d;
  asm("v_max3_f32 %0, %1, %2, %3" : "=v"(d) : "v"(a), "v"(b), "v"(c));
  return d;
}

// ---------------- transpose+cast 1024x1024 f32 weights -> bf16, 4 batched ----
struct T4 { const float* in[4]; u16* out[4]; };
__global__ __launch_bounds__(256) void transpose_w4(T4 p) {
  __shared__ u16 t[64][65];
  const float* in = p.in[blockIdx.z];
  u16* out = p.out[blockIdx.z];
  int r0 = blockIdx.y * 64, c0 = blockIdx.x * 64;
  for (int i = threadIdx.x; i < 4096; i += 256) {
    int r = i >> 6, c = i & 63;
    t[r][c] = f2bf(in[(size_t)(r0 + r) * 1024 + c0 + c]);
  }
  __syncthreads();
  for (int i = threadIdx.x; i < 4096; i += 256) {
    int r = i >> 6, c = i & 63;
    out[(size_t)(c0 + r) * 1024 + r0 + c] = t[c][r];
  }
}

// ---------------- fused cast+GEMM (m97 128x128 structure) ------------------
// C[M,N] = bf16(A_f32)[M,K] @ BT[N,K]^T. A reg-staged f32->bf16 via cvt_pk
// (swizzled ds_write); B via global_load_lds w16 (pre-swizzled source).
// z==2 (V): epilogue transposes tile in LDS, writes VT[bh][dk][s] coalesced.
struct QKV { const float* A[3]; const u16* BT[3]; u16* C[2]; u16* VT; };
__global__ __launch_bounds__(256) void gemm_qkv(QKV p) {
  constexpr int K = 1024, N = 1024;
  __shared__ __align__(16) u16 lbuf[2][128 * 64];  // lA | lB; reused as T
  const int tid = threadIdx.x, lane = tid & 63, w = tid >> 6;
  const int wr = w >> 1, wc = w & 1;
  const int z = blockIdx.z;
  const int m0 = blockIdx.x * 128, n0 = blockIdx.y * 128;
  const int g = lane >> 4, c16 = lane & 15;
  f32x4 acc[4][4] = {};
  const float* Af = p.A[z] + (size_t)m0 * K;
  const char* Bb = (const char*)(p.BT[z] + (size_t)n0 * K);
  char* lAb = (char*)lbuf[0];
  char* lBb = (char*)lbuf[1];
  for (int kt = 0; kt < K; kt += 64) {
    for (int c = 0; c < 4; ++c) {
      unsigned o = c * 4096 + tid * 16;
      unsigned u = swz128(o);
      gload_lds16(Bb + (size_t)(u >> 7) * (K * 2) + kt * 2 + (u & 127), lBb + o);
    }
    for (int c = 0; c < 4; ++c) {
      unsigned o = c * 4096 + tid * 16;       // linear bf16 byte offset
      unsigned row = o >> 7, kc = (o & 127) >> 1;
      const float* s = Af + (size_t)row * K + kt + kc;
      float4 f0 = *(const float4*)s;
      float4 f1 = *(const float4*)(s + 4);
      uint4v d;
      d[0] = cvtpk(f0.x, f0.y);
      d[1] = cvtpk(f0.z, f0.w);
      d[2] = cvtpk(f1.x, f1.y);
      d[3] = cvtpk(f1.z, f1.w);
      *(uint4v*)(lAb + swz128(o)) = d;
    }
    asm volatile("s_waitcnt vmcnt(0)" ::: "memory");
    __syncthreads();
    for (int ks = 0; ks < 2; ++ks) {
      bf16x8 af[4], bf[4];
      for (int i = 0; i < 4; ++i) {
        unsigned row = wr * 64 + i * 16 + c16;
        unsigned o = row * 128 + ks * 64 + g * 16;
        af[i] = *(const bf16x8*)(lAb + (o ^ ((row & 7) << 4)));
      }
      for (int j = 0; j < 4; ++j) {
        unsigned row = wc * 64 + j * 16 + c16;
        unsigned o = row * 128 + ks * 64 + g * 16;
        bf[j] = *(const bf16x8*)(lBb + (o ^ ((row & 7) << 4)));
      }
      for (int i = 0; i < 4; ++i)
        for (int j = 0; j < 4; ++j)
          acc[i][j] = __builtin_amdgcn_mfma_f32_16x16x32_bf16(af[i], bf[j],
                                                              acc[i][j], 0, 0, 0);
    }
    __syncthreads();
  }
  if (z < 2) {
    u16* C = p.C[z];
    for (int i = 0; i < 4; ++i)
      for (int j = 0; j < 4; ++j) {
        int row = m0 + wr * 64 + i * 16 + g * 4;
        int col = n0 + wc * 64 + j * 16 + c16;
        for (int r = 0; r < 4; ++r)
          C[(size_t)(row + r) * N + col] = f2bf(acc[i][j][r]);
      }
  } else {
    // V: transpose tile in LDS (T[dk_col][s_local], swz256 rows), then write
    // VT[bh][dk][s] as coalesced 256B runs.
    char* Tb = (char*)lbuf;
    for (int i = 0; i < 4; ++i)
      for (int j = 0; j < 4; ++j) {
        unsigned s_local = wr * 64 + i * 16 + g * 4;
        unsigned dk_col = wc * 64 + j * 16 + c16;
        unsigned o = dk_col * 256 + s_local * 2;
        u16x4 ov;
        ov[0] = f2bf(acc[i][j][0]);
        ov[1] = f2bf(acc[i][j][1]);
        ov[2] = f2bf(acc[i][j][2]);
        ov[3] = f2bf(acc[i][j][3]);
        *(u16x4*)(Tb + swz256(o)) = ov;
      }
    __syncthreads();
    const int b = m0 >> 11, s0blk = m0 & 2047;
    for (int c = 0; c < 8; ++c) {
      unsigned idx = c * 4096 + tid * 16;
      unsigned row = idx >> 8, off = idx & 255;  // row = dk_col
      int h = (n0 + (int)row) >> 6, dk = (n0 + (int)row) & 63;
      int bh = b * 16 + h;
      char* dst = (char*)p.VT + (((size_t)bh * 64 + dk) * S_ + s0blk) * 2 + off;
      *(u16x8*)dst = *(const u16x8*)(Tb + swz256(idx));
    }
  }
}

// ---------------- merge-scale micro-kernel ---------------------------------
// Per q-row: normalized scales (e0/l, e1/l) from the two halves' (m,l).
__global__ __launch_bounds__(256) void merge_ml(const float2* __restrict__ pML,
                                                float2* __restrict__ scl) {
  const float SC2 = 0.125f * 1.44269504088896340736f;
  int qr = blockIdx.x * 256 + threadIdx.x;  // 65536 total
  float2 ml0 = pML[qr];
  float2 ml1 = pML[65536 + qr];
  float m = fmaxf(ml0.x, ml1.x);
  float e0 = exp2f((ml0.x - m) * SC2);
  float e1 = exp2f((ml1.x - m) * SC2);
  float inv = 1.f / (ml0.y * e0 + ml1.y * e1);
  scl[qr] = make_float2(e0 * inv, e1 * inv);
}

// ---------------- final projection GEMM with fused partial-merge -----------
// C[M,N] = merge(pO0,pO1)[M,K] @ WoT[N,K]^T, f32 out. Tile 128x64, 4 waves.
// A-staging: load both bf16 partial chunks + scale pair, 2 fma/elem merge,
// cvt_pk, swizzled ds_write (gemm_qkv's verified reg-staged pattern).
__global__ __launch_bounds__(256) void gemm_merge_f32(const u16* __restrict__ pO,
                                                      const float2* __restrict__ scl,
                                                      const u16* __restrict__ BT,
                                                      float* __restrict__ C) {
  constexpr int K = 1024, N = 1024;
  __shared__ __align__(16) u16 lA[128 * 64];
  __shared__ __align__(16) u16 lB[64 * 64];
  const int tid = threadIdx.x, lane = tid & 63, w = tid >> 6;
  const int wr = w >> 1, wc = w & 1;
  const int m0 = blockIdx.x * 128, n0 = blockIdx.y * 64;
  const int g = lane >> 4, c16 = lane & 15;
  f32x4 acc[4][2] = {};
  const char* Bb = (const char*)(BT + (size_t)n0 * K);
  char* lAb = (char*)lA;
  char* lBb = (char*)lB;
  // per-thread A-chunk row constants (4 chunks: o = w*4096 + c*1024 + lane*16)
  // row = o>>7 in [0,128); global row = m0+row = b*2048+q.
  for (int kt = 0; kt < K; kt += 64) {
    for (int c = 0; c < 2; ++c) {
      unsigned o = w * 2048 + c * 1024 + lane * 16;
      unsigned u = swz128(o);
      gload_lds16(Bb + (size_t)(u >> 7) * (K * 2) + kt * 2 + (u & 127),
                  lBb + w * 2048 + c * 1024);
    }
    for (int c = 0; c < 4; ++c) {
      unsigned o = w * 4096 + c * 1024 + lane * 16;  // linear bf16 byte offset
      unsigned row = o >> 7, kc = (o & 127) >> 1;
      int ridx = m0 + (int)row;
      int b = ridx >> 11, q = ridx & 2047;
      int col = kt + (int)kc;
      int h = col >> 6, dk = col & 63;
      size_t qr = ((size_t)(b * 16 + h) << 11) + q;
      u16x8 a8 = *(const u16x8*)(pO + qr * 64 + dk);
      u16x8 c8 = *(const u16x8*)(pO + (qr + 65536) * 64 + dk);
      float2 sc = scl[qr];
      uint4v d;
      for (int e = 0; e < 4; ++e) {
        float lo = bf2f(a8[e * 2]) * sc.x + bf2f(c8[e * 2]) * sc.y;
        float hi = bf2f(a8[e * 2 + 1]) * sc.x + bf2f(c8[e * 2 + 1]) * sc.y;
        d[e] = cvtpk(lo, hi);
      }
      *(uint4v*)(lAb + swz128(o)) = d;
    }
    asm volatile("s_waitcnt vmcnt(0)" ::: "memory");
    __syncthreads();
    for (int ks = 0; ks < 2; ++ks) {
      bf16x8 af[4], bf[2];
      for (int i = 0; i < 4; ++i) {
        unsigned row = wr * 64 + i * 16 + c16;
        unsigned o = row * 128 + ks * 64 + g * 16;
        af[i] = *(const bf16x8*)(lAb + (o ^ ((row & 7) << 4)));
      }
      for (int j = 0; j < 2; ++j) {
        unsigned row = wc * 32 + j * 16 + c16;
        unsigned o = row * 128 + ks * 64 + g * 16;
        bf[j] = *(const bf16x8*)(lBb + (o ^ ((row & 7) << 4)));
      }
      for (int i = 0; i < 4; ++i)
        for (int j = 0; j < 2; ++j)
          acc[i][j] = __builtin_amdgcn_mfma_f32_16x16x32_bf16(af[i], bf[j],
                                                              acc[i][j], 0, 0, 0);
    }
    __syncthreads();
  }
  for (int i = 0; i < 4; ++i)
    for (int j = 0; j < 2; ++j) {
      int row = m0 + wr * 64 + i * 16 + g * 4;
      int col = n0 + wc * 32 + j * 16 + c16;
      for (int r = 0; r < 4; ++r)
        C[(size_t)(row + r) * N + col] = acc[i][j][r];
    }
}

// ---------------- flash attention v10: KV-split, single-buffer, partials ---
// grid flat 2048: (bh, half, qtile). 4 waves, wave w owns q rows [w*16,+16).
// Each block covers HALF the kv range (16 tiles), emits un-normalized
// partials (O*, m, l); merge fused into final GEMM. (r17-measured: 84 us)
__global__ __launch_bounds__(256) void flash_attn(const u16* __restrict__ Q,
                                                  const u16* __restrict__ K,
                                                  const u16* __restrict__ VT,
                                                  u16* __restrict__ pO,
                                                  float2* __restrict__ pML) {
  __shared__ __align__(16) u16 lP[64 * 64];   // Q staging, then P tile
  __shared__ __align__(16) u16 lK[64 * 64];   // single-buffered
  __shared__ __align__(16) u16 lV[64 * 64];
  const int tid = threadIdx.x, lane = tid & 63, w = tid >> 6;
  const int g = lane >> 4, c16 = lane & 15;
  // XCD swizzle: nwg=2048, chunk 256 -> each XCD owns 4 full (b,h) pairs
  unsigned sw = xcd_swz(blockIdx.x, 256);
  const int q0 = (sw & 31) * 64;
  const int half = (sw >> 5) & 1;
  const int bh = sw >> 6, b = bh >> 4, h = bh & 15;
  const int kv_base = half * (S_ / 2);
  const char* Qb = (const char*)(Q + (size_t)(b * S_ + q0) * D_ + h * 64);
  const char* Kb = (const char*)(K + (size_t)b * S_ * D_ + h * 64);
  const char* Vb = (const char*)(VT + (size_t)bh * 64 * S_);
  char* lPb = (char*)lP;
  char* lKb = (char*)lK;
  char* lVb = (char*)lV;

  // lane-constant swizzled fragment bases (row&7 == c16&7 for all rows used)
  const unsigned mask = (c16 & 7) << 4;
  const unsigned fb0 = c16 * 128 + ((g * 16) ^ mask);
  const unsigned fb1 = c16 * 128 + ((64 + g * 16) ^ mask);
  unsigned uo[2];
  for (int c = 0; c < 2; ++c) uo[c] = swz128(w * 2048 + c * 1024 + lane * 16);

  for (int c = 0; c < 2; ++c) {
    unsigned u = uo[c];
    unsigned dst = w * 2048 + c * 1024;
    gload_lds16(Qb + (size_t)(u >> 7) * (D_ * 2) + (u & 127), lPb + dst);
    gload_lds16(Kb + (size_t)(kv_base + (u >> 7)) * (D_ * 2) + (u & 127), lKb + dst);
    gload_lds16(Vb + (size_t)(u >> 7) * (S_ * 2) + (size_t)kv_base * 2 + (u & 127), lVb + dst);
  }
  float m_run = -INFINITY, l_run = 0.f;
  f32x4 oacc[4] = {};  // oacc[i][r] = O^T[dk=i*16+g*4+r][q=w*16+c16]
  asm volatile("s_waitcnt vmcnt(0)" ::: "memory");
  __syncthreads();
  bf16x8 qf[2];
  qf[0] = *(const bf16x8*)(lPb + w * 2048 + fb0);
  qf[1] = *(const bf16x8*)(lPb + w * 2048 + fb1);
  const float SC2 = 0.125f * 1.44269504088896340736f;  // SCALE * log2(e)
  const unsigned qrow = w * 16 + c16;
  const unsigned pw = qrow * 128 + ((g * 8) ^ (mask & 16));
  const unsigned mh = mask & 96;
  for (int t = 0; t < 16; ++t) {
    // S^T = K Q^T: s[j][r] = S[kv=j*16+g*4+r][q=w*16+c16]
    f32x4 s[4] = {};
    __builtin_amdgcn_s_setprio(1);
    for (int j = 0; j < 4; ++j) {
      bf16x8 kf = *(const bf16x8*)(lKb + fb0 + j * 2048);
      s[j] = __builtin_amdgcn_mfma_f32_16x16x32_bf16(kf, qf[0], s[j], 0, 0, 0);
    }
    for (int j = 0; j < 4; ++j) {
      bf16x8 kf = *(const bf16x8*)(lKb + fb1 + j * 2048);
      s[j] = __builtin_amdgcn_mfma_f32_16x16x32_bf16(kf, qf[1], s[j], 0, 0, 0);
    }
    __builtin_amdgcn_s_setprio(0);
    // row max: max3 tree (depth 3)
    float t0 = max3f(s[0][0], s[0][1], s[0][2]);
    float t1 = max3f(s[0][3], s[1][0], s[1][1]);
    float t2 = max3f(s[1][2], s[1][3], s[2][0]);
    float t3 = max3f(s[2][1], s[2][2], s[2][3]);
    float t4 = max3f(s[3][0], s[3][1], s[3][2]);
    float rm = fmaxf(max3f(t0, t1, t2), max3f(t3, t4, s[3][3]));
    rm = fmaxf(rm, __shfl_xor(rm, 16));
    rm = fmaxf(rm, __shfl_xor(rm, 32));
    // T13 defer-rescale
    if (!__all((rm - m_run) * SC2 <= 8.0f)) {
      float mn = fmaxf(m_run, rm);
      float sc = exp2f((m_run - mn) * SC2);
      l_run *= sc;
      for (int i = 0; i < 4; ++i) oacc[i] *= sc;
      m_run = mn;
    }
    for (int j = 0; j < 4; ++j) {
      float p0 = exp2f((s[j][0] - m_run) * SC2);
      float p1 = exp2f((s[j][1] - m_run) * SC2);
      float p2 = exp2f((s[j][2] - m_run) * SC2);
      float p3 = exp2f((s[j][3] - m_run) * SC2);
      l_run += (p0 + p1) + (p2 + p3);   // deferred: per-lane partial only
      unsigned w0 = cvtpk(p0, p1);
      unsigned w1 = cvtpk(p2, p3);
      *(u64*)(lPb + pw + ((unsigned)(j * 32) ^ mh)) = (u64)w0 | ((u64)w1 << 32);
    }
    // O^T += V^T P
    __builtin_amdgcn_s_setprio(1);
    {
      bf16x8 pf0 = *(const bf16x8*)(lPb + w * 2048 + fb0);
      for (int i = 0; i < 4; ++i) {
        bf16x8 vf = *(const bf16x8*)(lVb + fb0 + i * 2048);
        oacc[i] = __builtin_amdgcn_mfma_f32_16x16x32_bf16(vf, pf0, oacc[i], 0, 0, 0);
      }
      bf16x8 pf1 = *(const bf16x8*)(lPb + w * 2048 + fb1);
      for (int i = 0; i < 4; ++i) {
        bf16x8 vf = *(const bf16x8*)(lVb + fb1 + i * 2048);
        oacc[i] = __builtin_amdgcn_mfma_f32_16x16x32_bf16(vf, pf1, oacc[i], 0, 0, 0);
      }
    }
    __builtin_amdgcn_s_setprio(0);
    __syncthreads();  // all waves done reading lK/lV this tile
    if (t < 15) {     // single-buffer restage; drain own loads, then barrier
      int kv_next = kv_base + (t + 1) * 64;
      for (int c = 0; c < 2; ++c) {
        unsigned u = uo[c];
        unsigned dst = w * 2048 + c * 1024;
        gload_lds16(Kb + (size_t)(kv_next + (u >> 7)) * (D_ * 2) + (u & 127),
                    lKb + dst);
        gload_lds16(Vb + (size_t)(u >> 7) * (S_ * 2) + (size_t)kv_next * 2 + (u & 127),
                    lVb + dst);
      }
      asm volatile("s_waitcnt vmcnt(0)" ::: "memory");
    }
    __syncthreads();
  }
  // epilogue: reduce deferred l across the 4 g-lanes; write partials
  l_run += __shfl_xor(l_run, 16);
  l_run += __shfl_xor(l_run, 32);
  const size_t qr = (size_t)(half * 32 + bh) * S_ + (q0 + qrow);
  u16* po = pO + qr * 64;
  for (int i = 0; i < 4; ++i) {
    unsigned e0 = cvtpk(oacc[i][0], oacc[i][1]);
    unsigned e1 = cvtpk(oacc[i][2], oacc[i][3]);
    *(u64*)(po + i * 16 + g * 4) = (u64)e0 | ((u64)e1 << 32);
  }
  if (g == 0) pML[qr] = make_float2(m_run, l_run);
}

extern "C" void kernel_launch(void* const* d_in, const int* in_sizes, int n_in,
                              void* d_out, int out_size, void* d_ws, size_t ws_size,
                              hipStream_t stream) {
  const float* q_in = (const float*)d_in[0];
  const float* k_in = (const float*)d_in[1];
  const float* v_in = (const float*)d_in[2];
  const float* Wq = (const float*)d_in[3];
  const float* Wk = (const float*)d_in[4];
  const float* Wv = (const float*)d_in[5];
  const float* Wo = (const float*)d_in[6];
  u16* ws = (u16*)d_ws;
  const size_t WSZ = (size_t)1024 * 1024;
  const size_t TSZ = (size_t)B_ * S_ * D_;  // 4,194,304
  u16* WqT = ws;
  u16* WkT = ws + WSZ;
  u16* WvT = ws + 2 * WSZ;
  u16* WoT = ws + 3 * WSZ;
  u16* Qb = ws + 4 * WSZ;
  u16* Kb = Qb + TSZ;
  u16* VTb = Kb + TSZ;
  u16* pO = VTb + TSZ;                    // 2 x TSZ (bf16 partials)
  float2* pML = (float2*)(pO + 2 * TSZ);  // 131072 float2 = 1 MB
  float2* scl = pML + 131072;             // 65536 float2 = 512 KB
  dim3 tb(256);
  T4 tw = {{Wq, Wk, Wv, Wo}, {WqT, WkT, WvT, WoT}};
  transpose_w4<<<dim3(16, 16, 4), tb, 0, stream>>>(tw);
  QKV gq = {{q_in, k_in, v_in}, {WqT, WkT, WvT}, {Qb, Kb}, VTb};
  gemm_qkv<<<dim3(32, 8, 3), tb, 0, stream>>>(gq);
  flash_attn<<<dim3(2048), tb, 0, stream>>>(Qb, Kb, VTb, pO, pML);
  merge_ml<<<dim3(256), tb, 0, stream>>>(pML, scl);
  gemm_merge_f32<<<dim3(32, 16), tb, 0, stream>>>(pO, scl, WoT, (float*)d_out);
}

// Round 19
// 153.505 us; speedup vs baseline: 1.1179x; 1.1179x over previous
//
#include <hip/hip_runtime.h>

#define B_ 2
#define S_ 2048
#define D_ 1024
#define H_ 16

typedef unsigned short u16;
typedef unsigned long long u64;
typedef __bf16 bf16x8 __attribute__((ext_vector_type(8)));
typedef float f32x4 __attribute__((ext_vector_type(4)));
typedef unsigned short u16x8 __attribute__((ext_vector_type(8)));
typedef unsigned short u16x4 __attribute__((ext_vector_type(4)));
typedef unsigned uint4v __attribute__((ext_vector_type(4)));

__device__ __forceinline__ unsigned swz128(unsigned o) {  // 128B rows
  return o ^ (((o >> 7) & 7) << 4);
}
__device__ __forceinline__ unsigned swz256(unsigned o) {  // 256B rows
  return o ^ (((o >> 8) & 7) << 4);
}

// bijective XCD-aware remap (nwg % 8 == 0): XCD x gets contiguous chunk.
__device__ __forceinline__ unsigned xcd_swz(unsigned id, unsigned cpx) {
  return (id & 7) * cpx + (id >> 3);
}

__device__ __forceinline__ void gload_lds16(const void* g, void* l) {
  __builtin_amdgcn_global_load_lds(
      (const __attribute__((address_space(1))) unsigned*)g,
      (__attribute__((address_space(3))) unsigned*)l, 16, 0, 0);
}

__device__ __forceinline__ u16 f2bf(float f) {
  union { float f; unsigned u; } v;
  v.f = f;
  unsigned u = v.u;
  return (u16)((u + 0x7fffu + ((u >> 16) & 1u)) >> 16);
}

// RNE pack of two f32 -> one dword of 2 bf16 (lo,hi). gfx950 HW instruction.
__device__ __forceinline__ unsigned cvtpk(float lo, float hi) {
  unsigned d;
  asm("v_cvt_pk_bf16_f32 %0, %1, %2" : "=v"(d) : "v"(lo), "v"(hi));
  return d;
}

__device__ __forceinline__ float max3f(float a, float b, float c) {
  float d;
  asm("v_max3_f32 %0, %1, %2, %3" : "=v"(d) : "v"(a), "v"(b), "v"(c));
  return d;
}

// ---------------- transpose+cast 1024x1024 f32 weights -> bf16, 4 batched ----
struct T4 { const float* in[4]; u16* out[4]; };
__global__ __launch_bounds__(256) void transpose_w4(T4 p) {
  __shared__ u16 t[64][65];
  const float* in = p.in[blockIdx.z];
  u16* out = p.out[blockIdx.z];
  int r0 = blockIdx.y * 64, c0 = blockIdx.x * 64;
  for (int i = threadIdx.x; i < 4096; i += 256) {
    int r = i >> 6, c = i & 63;
    t[r][c] = f2bf(in[(size_t)(r0 + r) * 1024 + c0 + c]);
  }
  __syncthreads();
  for (int i = threadIdx.x; i < 4096; i += 256) {
    int r = i >> 6, c = i & 63;
    out[(size_t)(c0 + r) * 1024 + r0 + c] = t[c][r];
  }
}

// ---------------- fused cast+GEMM (m97 128x128 structure) ------------------
// C[M,N] = bf16(A_f32)[M,K] @ BT[N,K]^T. A reg-staged f32->bf16 via cvt_pk
// (swizzled ds_write); B via global_load_lds w16 (pre-swizzled source).
// z==2 (V): epilogue transposes tile in LDS, writes VT[bh][dk][s] coalesced.
struct QKV { const float* A[3]; const u16* BT[3]; u16* C[2]; u16* VT; };
__global__ __launch_bounds__(256) void gemm_qkv(QKV p) {
  constexpr int K = 1024, N = 1024;
  __shared__ __align__(16) u16 lbuf[2][128 * 64];  // lA | lB; reused as T
  const int tid = threadIdx.x, lane = tid & 63, w = tid >> 6;
  const int wr = w >> 1, wc = w & 1;
  const int z = blockIdx.z;
  const int m0 = blockIdx.x * 128, n0 = blockIdx.y * 128;
  const int g = lane >> 4, c16 = lane & 15;
  f32x4 acc[4][4] = {};
  const float* Af = p.A[z] + (size_t)m0 * K;
  const char* Bb = (const char*)(p.BT[z] + (size_t)n0 * K);
  char* lAb = (char*)lbuf[0];
  char* lBb = (char*)lbuf[1];
  for (int kt = 0; kt < K; kt += 64) {
    for (int c = 0; c < 4; ++c) {
      unsigned o = c * 4096 + tid * 16;
      unsigned u = swz128(o);
      gload_lds16(Bb + (size_t)(u >> 7) * (K * 2) + kt * 2 + (u & 127), lBb + o);
    }
    for (int c = 0; c < 4; ++c) {
      unsigned o = c * 4096 + tid * 16;       // linear bf16 byte offset
      unsigned row = o >> 7, kc = (o & 127) >> 1;
      const float* s = Af + (size_t)row * K + kt + kc;
      float4 f0 = *(const float4*)s;
      float4 f1 = *(const float4*)(s + 4);
      uint4v d;
      d[0] = cvtpk(f0.x, f0.y);
      d[1] = cvtpk(f0.z, f0.w);
      d[2] = cvtpk(f1.x, f1.y);
      d[3] = cvtpk(f1.z, f1.w);
      *(uint4v*)(lAb + swz128(o)) = d;
    }
    asm volatile("s_waitcnt vmcnt(0)" ::: "memory");
    __syncthreads();
    for (int ks = 0; ks < 2; ++ks) {
      bf16x8 af[4], bf[4];
      for (int i = 0; i < 4; ++i) {
        unsigned row = wr * 64 + i * 16 + c16;
        unsigned o = row * 128 + ks * 64 + g * 16;
        af[i] = *(const bf16x8*)(lAb + (o ^ ((row & 7) << 4)));
      }
      for (int j = 0; j < 4; ++j) {
        unsigned row = wc * 64 + j * 16 + c16;
        unsigned o = row * 128 + ks * 64 + g * 16;
        bf[j] = *(const bf16x8*)(lBb + (o ^ ((row & 7) << 4)));
      }
      for (int i = 0; i < 4; ++i)
        for (int j = 0; j < 4; ++j)
          acc[i][j] = __builtin_amdgcn_mfma_f32_16x16x32_bf16(af[i], bf[j],
                                                              acc[i][j], 0, 0, 0);
    }
    __syncthreads();
  }
  if (z < 2) {
    u16* C = p.C[z];
    for (int i = 0; i < 4; ++i)
      for (int j = 0; j < 4; ++j) {
        int row = m0 + wr * 64 + i * 16 + g * 4;
        int col = n0 + wc * 64 + j * 16 + c16;
        for (int r = 0; r < 4; ++r)
          C[(size_t)(row + r) * N + col] = f2bf(acc[i][j][r]);
      }
  } else {
    // V: transpose tile in LDS (T[dk_col][s_local], swz256 rows), then write
    // VT[bh][dk][s] as coalesced 256B runs.
    char* Tb = (char*)lbuf;
    for (int i = 0; i < 4; ++i)
      for (int j = 0; j < 4; ++j) {
        unsigned s_local = wr * 64 + i * 16 + g * 4;
        unsigned dk_col = wc * 64 + j * 16 + c16;
        unsigned o = dk_col * 256 + s_local * 2;
        u16x4 ov;
        ov[0] = f2bf(acc[i][j][0]);
        ov[1] = f2bf(acc[i][j][1]);
        ov[2] = f2bf(acc[i][j][2]);
        ov[3] = f2bf(acc[i][j][3]);
        *(u16x4*)(Tb + swz256(o)) = ov;
      }
    __syncthreads();
    const int b = m0 >> 11, s0blk = m0 & 2047;
    for (int c = 0; c < 8; ++c) {
      unsigned idx = c * 4096 + tid * 16;
      unsigned row = idx >> 8, off = idx & 255;  // row = dk_col
      int h = (n0 + (int)row) >> 6, dk = (n0 + (int)row) & 63;
      int bh = b * 16 + h;
      char* dst = (char*)p.VT + (((size_t)bh * 64 + dk) * S_ + s0blk) * 2 + off;
      *(u16x8*)dst = *(const u16x8*)(Tb + swz256(idx));
    }
  }
}

// ---------------- GEMM (bf16 A): final projection, f32 out ------------------
// Tile 128x64, BK=64, 4 waves (2x2), 512 blocks. Round-13 verified version.
__global__ __launch_bounds__(256) void gemm_bt_f32(const u16* __restrict__ A,
                                                   const u16* __restrict__ BT,
                                                   float* __restrict__ C) {
  constexpr int K = 1024, N = 1024;
  __shared__ __align__(16) u16 lA[128 * 64];
  __shared__ __align__(16) u16 lB[64 * 64];
  const int tid = threadIdx.x, lane = tid & 63, w = tid >> 6;
  const int wr = w >> 1, wc = w & 1;
  const int m0 = blockIdx.x * 128, n0 = blockIdx.y * 64;
  const int g = lane >> 4, c16 = lane & 15;
  f32x4 acc[4][2] = {};
  const char* Ab = (const char*)(A + (size_t)m0 * K);
  const char* Bb = (const char*)(BT + (size_t)n0 * K);
  char* lAb = (char*)lA;
  char* lBb = (char*)lB;
  for (int kt = 0; kt < K; kt += 64) {
    for (int c = 0; c < 4; ++c) {
      unsigned o = w * 4096 + c * 1024 + lane * 16;
      unsigned u = swz128(o);
      gload_lds16(Ab + (size_t)(u >> 7) * (K * 2) + kt * 2 + (u & 127),
                  lAb + w * 4096 + c * 1024);
    }
    for (int c = 0; c < 2; ++c) {
      unsigned o = w * 2048 + c * 1024 + lane * 16;
      unsigned u = swz128(o);
      gload_lds16(Bb + (size_t)(u >> 7) * (K * 2) + kt * 2 + (u & 127),
                  lBb + w * 2048 + c * 1024);
    }
    asm volatile("s_waitcnt vmcnt(0)" ::: "memory");
    __syncthreads();
    for (int ks = 0; ks < 2; ++ks) {
      bf16x8 af[4], bf[2];
      for (int i = 0; i < 4; ++i) {
        unsigned row = wr * 64 + i * 16 + c16;
        unsigned o = row * 128 + ks * 64 + g * 16;
        af[i] = *(const bf16x8*)(lAb + (o ^ ((row & 7) << 4)));
      }
      for (int j = 0; j < 2; ++j) {
        unsigned row = wc * 32 + j * 16 + c16;
        unsigned o = row * 128 + ks * 64 + g * 16;
        bf[j] = *(const bf16x8*)(lBb + (o ^ ((row & 7) << 4)));
      }
      for (int i = 0; i < 4; ++i)
        for (int j = 0; j < 2; ++j)
          acc[i][j] = __builtin_amdgcn_mfma_f32_16x16x32_bf16(af[i], bf[j],
                                                              acc[i][j], 0, 0, 0);
    }
    __syncthreads();
  }
  for (int i = 0; i < 4; ++i)
    for (int j = 0; j < 2; ++j) {
      int row = m0 + wr * 64 + i * 16 + g * 4;
      int col = n0 + wc * 32 + j * 16 + c16;
      for (int r = 0; r < 4; ++r)
        C[(size_t)(row + r) * N + col] = acc[i][j][r];
    }
}

// ---------------- flash attention v9 (round-16 best: 87.4 us) --------------
// grid flat 1024; 4 waves, wave w owns q rows [w*16, w*16+16).
// S^T = mfma(K,Q): lane owns ONE q-row (q=w*16+c16), 16 kv-scores in regs.
// All LDS frag addrs = lane-const base + compile-time imm. Deferred-l.
__global__ __launch_bounds__(256) void flash_attn(const u16* __restrict__ Q,
                                                  const u16* __restrict__ K,
                                                  const u16* __restrict__ VT,
                                                  u16* __restrict__ O) {
  __shared__ __align__(16) u16 lP[64 * 64];      // Q staging, then P tile
  __shared__ __align__(16) u16 lK[2][64 * 64];   // double-buffered
  __shared__ __align__(16) u16 lV[2][64 * 64];
  const int tid = threadIdx.x, lane = tid & 63, w = tid >> 6;
  const int g = lane >> 4, c16 = lane & 15;
  // XCD swizzle: nwg=1024, chunk 128 -> each XCD owns 4 full (b,h) pairs
  unsigned id = blockIdx.x + blockIdx.y * gridDim.x;
  unsigned sw = xcd_swz(id, 128);
  const int q0 = (sw & 31) * 64;
  const int bh = sw >> 5, b = bh >> 4, h = bh & 15;
  const char* Qb = (const char*)(Q + (size_t)(b * S_ + q0) * D_ + h * 64);
  const char* Kb = (const char*)(K + (size_t)b * S_ * D_ + h * 64);
  const char* Vb = (const char*)(VT + (size_t)bh * 64 * S_);
  char* lPb = (char*)lP;
  char* lKb = (char*)lK;
  char* lVb = (char*)lV;

  // lane-constant swizzled fragment bases (row&7 == c16&7 for all rows used)
  const unsigned mask = (c16 & 7) << 4;
  const unsigned fb0 = c16 * 128 + ((g * 16) ^ mask);
  const unsigned fb1 = c16 * 128 + ((64 + g * 16) ^ mask);
  unsigned uo[2];
  for (int c = 0; c < 2; ++c) uo[c] = swz128(w * 2048 + c * 1024 + lane * 16);

  for (int c = 0; c < 2; ++c) {
    unsigned u = uo[c];
    unsigned dst = w * 2048 + c * 1024;
    gload_lds16(Qb + (size_t)(u >> 7) * (D_ * 2) + (u & 127), lPb + dst);
    gload_lds16(Kb + (size_t)(u >> 7) * (D_ * 2) + (u & 127), lKb + dst);
    gload_lds16(Vb + (size_t)(u >> 7) * (S_ * 2) + (u & 127), lVb + dst);
  }
  float m_run = -INFINITY, l_run = 0.f;
  f32x4 oacc[4] = {};  // oacc[i][r] = O^T[dk=i*16+g*4+r][q=w*16+c16]
  asm volatile("s_waitcnt vmcnt(0)" ::: "memory");
  __syncthreads();
  bf16x8 qf[2];
  qf[0] = *(const bf16x8*)(lPb + w * 2048 + fb0);
  qf[1] = *(const bf16x8*)(lPb + w * 2048 + fb1);
  const float SC2 = 0.125f * 1.44269504088896340736f;  // SCALE * log2(e)
  const unsigned qrow = w * 16 + c16;
  const unsigned pw = qrow * 128 + ((g * 8) ^ (mask & 16));
  const unsigned mh = mask & 96;
  int cur = 0;
  for (int kv0 = 0; kv0 < S_; kv0 += 64, cur ^= 1) {
    const char* curK = lKb + cur * 8192;
    const char* curV = lVb + cur * 8192;
    if (kv0 + 64 < S_) {  // T3: next tile staging issued before compute
      char* nK = lKb + (cur ^ 1) * 8192;
      char* nV = lVb + (cur ^ 1) * 8192;
      for (int c = 0; c < 2; ++c) {
        unsigned u = uo[c];
        unsigned dst = w * 2048 + c * 1024;
        gload_lds16(Kb + (size_t)(kv0 + 64 + (u >> 7)) * (D_ * 2) + (u & 127),
                    nK + dst);
        gload_lds16(Vb + (size_t)(u >> 7) * (S_ * 2) + (size_t)(kv0 + 64) * 2 + (u & 127),
                    nV + dst);
      }
    }
    // S^T = K Q^T: s[j][r] = S[kv=j*16+g*4+r][q=w*16+c16]
    f32x4 s[4] = {};
    __builtin_amdgcn_s_setprio(1);
    for (int j = 0; j < 4; ++j) {
      bf16x8 kf = *(const bf16x8*)(curK + fb0 + j * 2048);
      s[j] = __builtin_amdgcn_mfma_f32_16x16x32_bf16(kf, qf[0], s[j], 0, 0, 0);
    }
    for (int j = 0; j < 4; ++j) {
      bf16x8 kf = *(const bf16x8*)(curK + fb1 + j * 2048);
      s[j] = __builtin_amdgcn_mfma_f32_16x16x32_bf16(kf, qf[1], s[j], 0, 0, 0);
    }
    __builtin_amdgcn_s_setprio(0);
    // row max: max3 tree (depth 3)
    float t0 = max3f(s[0][0], s[0][1], s[0][2]);
    float t1 = max3f(s[0][3], s[1][0], s[1][1]);
    float t2 = max3f(s[1][2], s[1][3], s[2][0]);
    float t3 = max3f(s[2][1], s[2][2], s[2][3]);
    float t4 = max3f(s[3][0], s[3][1], s[3][2]);
    float rm = fmaxf(max3f(t0, t1, t2), max3f(t3, t4, s[3][3]));
    rm = fmaxf(rm, __shfl_xor(rm, 16));
    rm = fmaxf(rm, __shfl_xor(rm, 32));
    // T13 defer-rescale
    if (!__all((rm - m_run) * SC2 <= 8.0f)) {
      float mn = fmaxf(m_run, rm);
      float sc = exp2f((m_run - mn) * SC2);
      l_run *= sc;
      for (int i = 0; i < 4; ++i) oacc[i] *= sc;
      m_run = mn;
    }
    float rsj[4];
    for (int j = 0; j < 4; ++j) {
      float p0 = exp2f((s[j][0] - m_run) * SC2);
      float p1 = exp2f((s[j][1] - m_run) * SC2);
      float p2 = exp2f((s[j][2] - m_run) * SC2);
      float p3 = exp2f((s[j][3] - m_run) * SC2);
      rsj[j] = (p0 + p1) + (p2 + p3);
      unsigned w0 = cvtpk(p0, p1);
      unsigned w1 = cvtpk(p2, p3);
      *(u64*)(lPb + pw + ((unsigned)(j * 32) ^ mh)) = (u64)w0 | ((u64)w1 << 32);
    }
    // deferred l: per-lane partial only (sc is g-uniform; reduce at epilogue)
    l_run += (rsj[0] + rsj[1]) + (rsj[2] + rsj[3]);
    // O^T += V^T P
    __builtin_amdgcn_s_setprio(1);
    {
      bf16x8 pf0 = *(const bf16x8*)(lPb + w * 2048 + fb0);
      for (int i = 0; i < 4; ++i) {
        bf16x8 vf = *(const bf16x8*)(curV + fb0 + i * 2048);
        oacc[i] = __builtin_amdgcn_mfma_f32_16x16x32_bf16(vf, pf0, oacc[i], 0, 0, 0);
      }
      bf16x8 pf1 = *(const bf16x8*)(lPb + w * 2048 + fb1);
      for (int i = 0; i < 4; ++i) {
        bf16x8 vf = *(const bf16x8*)(curV + fb1 + i * 2048);
        oacc[i] = __builtin_amdgcn_mfma_f32_16x16x32_bf16(vf, pf1, oacc[i], 0, 0, 0);
      }
    }
    __builtin_amdgcn_s_setprio(0);
    asm volatile("s_waitcnt vmcnt(0)" ::: "memory");
    __syncthreads();
  }
  // epilogue: reduce deferred l across the 4 g-lanes of this q-row
  l_run += __shfl_xor(l_run, 16);
  l_run += __shfl_xor(l_run, 32);
  float inv = 1.f / l_run;
  int q = q0 + w * 16 + c16;
  u16* orow = O + (size_t)(b * S_ + q) * D_ + h * 64;
  for (int i = 0; i < 4; ++i) {
    unsigned e0 = cvtpk(oacc[i][0] * inv, oacc[i][1] * inv);
    unsigned e1 = cvtpk(oacc[i][2] * inv, oacc[i][3] * inv);
    *(u64*)(orow + i * 16 + g * 4) = (u64)e0 | ((u64)e1 << 32);
  }
}

extern "C" void kernel_launch(void* const* d_in, const int* in_sizes, int n_in,
                              void* d_out, int out_size, void* d_ws, size_t ws_size,
                              hipStream_t stream) {
  const float* q_in = (const float*)d_in[0];
  const float* k_in = (const float*)d_in[1];
  const float* v_in = (const float*)d_in[2];
  const float* Wq = (const float*)d_in[3];
  const float* Wk = (const float*)d_in[4];
  const float* Wv = (const float*)d_in[5];
  const float* Wo = (const float*)d_in[6];
  u16* ws = (u16*)d_ws;
  const size_t WSZ = (size_t)1024 * 1024;
  const size_t TSZ = (size_t)B_ * S_ * D_;  // 4,194,304
  u16* WqT = ws;
  u16* WkT = ws + WSZ;
  u16* WvT = ws + 2 * WSZ;
  u16* WoT = ws + 3 * WSZ;
  u16* Qb = ws + 4 * WSZ;
  u16* Kb = Qb + TSZ;
  u16* VTb = Kb + TSZ;
  u16* Ob = VTb + TSZ;
  dim3 tb(256);
  T4 tw = {{Wq, Wk, Wv, Wo}, {WqT, WkT, WvT, WoT}};
  transpose_w4<<<dim3(16, 16, 4), tb, 0, stream>>>(tw);
  QKV gq = {{q_in, k_in, v_in}, {WqT, WkT, WvT}, {Qb, Kb}, VTb};
  gemm_qkv<<<dim3(32, 8, 3), tb, 0, stream>>>(gq);
  flash_attn<<<dim3(32, 32), tb, 0, stream>>>(Qb, Kb, VTb, Ob);
  gemm_bt_f32<<<dim3(32, 16), tb, 0, stream>>>(Ob, WoT, (float*)d_out);
}